// Round 1
// 493.188 us; speedup vs baseline: 1.1717x; 1.1717x over previous
//
#include <hip/hip_runtime.h>
#include <math.h>

#define NN 512
#define RR 262144  // NN*NN
#define EPS_F 1e-5f

typedef unsigned short u16;
typedef unsigned int u32;
typedef __bf16 bf16x8 __attribute__((ext_vector_type(8)));
typedef float f32x4 __attribute__((ext_vector_type(4)));

__device__ __forceinline__ u16 f2bs(float f) {
  __bf16 h = (__bf16)f;
  return __builtin_bit_cast(u16, h);
}
__device__ __forceinline__ float bs2f(u16 u) {
  return (float)__builtin_bit_cast(__bf16, u);
}
__device__ __forceinline__ float sigmoidf_(float x) {
  return 1.f / (1.f + __expf(-x));
}

// ---------------- Kernel W: weight convert fp32->bf16, MFMA-fragment order ----
// New wb layout: element slot u = ((((tt*2+wn)*4+nt)*4+ks)*64 + lane)*8 holds
// W_tile[tt][n = wn*64+nt*16+(lane&15)][k = ks*32+(lane>>4)*8 + e], e=0..7.
// So in k_proj a wave loads fragment (nt,ks) as ONE coalesced 16B/lane load:
// wb + (tt*2+wn)*8192 + (nt*4+ks)*512 + lane*8.
// Column mapping inside a 128-col tile is unchanged from before:
// n -> srow = tt*64 + ((n>>5)<<4) + (n&15) of (bit4(n) ? w_ab_g : w_ab_p);
// tile 4 = w_g rows directly.
__global__ __launch_bounds__(256) void k_wconv(const float* __restrict__ w_ab_p,
                                               const float* __restrict__ w_ab_g,
                                               const float* __restrict__ w_g,
                                               u16* __restrict__ wb) {
  const int u = blockIdx.x * 256 + threadIdx.x;  // 0..10239, 8 bf16 each
  const int lane = u & 63;
  const int tl = lane & 15, quad = lane >> 4;
  const int ks = (u >> 6) & 3, nt = (u >> 8) & 3;
  const int wn = (u >> 10) & 1, tt = u >> 11;
  const int n = wn * 64 + nt * 16 + tl;
  const int k = ks * 32 + quad * 8;
  const float* src;
  if (tt < 4) {
    const int srow = tt * 64 + ((n >> 5) << 4) + (n & 15);
    src = (((n >> 4) & 1) ? w_ab_g : w_ab_p) + srow * 128 + k;
  } else {
    src = w_g + n * 128 + k;
  }
  const float4 v0 = *(const float4*)src;
  const float4 v1 = *(const float4*)(src + 4);
  u16 o[8] = {f2bs(v0.x), f2bs(v0.y), f2bs(v0.z), f2bs(v0.w),
              f2bs(v1.x), f2bs(v1.y), f2bs(v1.z), f2bs(v1.w)};
  *(uint4*)(wb + (long)u * 8) = *(uint4*)o;
}

// ---------------- Kernel B: fused LN(z) + all projections ----------------
// grid R/128. LN 128 rows of z into As (bf16). Weights are NOT LDS-staged:
// each wave loads its 16 B-fragments per tile directly from L2-resident wb
// (coalesced 16B/lane). LDS = As(34.8K) + Ts(17.4K transpose scratch) + mask
// = 52.7 KB -> 3 blocks/CU (was 70.1 KB -> 2). Barriers: 2/tile (was 4).
__global__ __launch_bounds__(256, 3) void k_proj(
    const float* __restrict__ z, const float* __restrict__ mask,
    const u16* __restrict__ wb, const float* __restrict__ b_ab_p,
    const float* __restrict__ b_ab_g, const float* __restrict__ b_g,
    const float* __restrict__ ln_g, const float* __restrict__ ln_b,
    u16* __restrict__ a_t, u16* __restrict__ b_t, u16* __restrict__ g_out) {
  __shared__ __align__(16) u16 As[128 * 136];
  __shared__ __align__(16) u16 Ts[64 * 136];
  __shared__ float maskS[128];
  const int t = threadIdx.x;
  const long row0 = (long)blockIdx.x * 128;

  {  // fused input LayerNorm: z fp32 -> bf16 zn tile in As. 2 threads/row.
    const int row = t >> 1, half = t & 1;
    const float* zr = z + (row0 + row) * 128 + half * 64;
    float vals[64];
    float s = 0.f, sq = 0.f;
#pragma unroll
    for (int i = 0; i < 16; ++i) {
      const float4 v = *(const float4*)(zr + i * 4);
      vals[i * 4 + 0] = v.x;
      vals[i * 4 + 1] = v.y;
      vals[i * 4 + 2] = v.z;
      vals[i * 4 + 3] = v.w;
      s += v.x + v.y + v.z + v.w;
      sq += v.x * v.x + v.y * v.y + v.z * v.z + v.w * v.w;
    }
    s += __shfl_xor(s, 1);
    sq += __shfl_xor(sq, 1);
    const float mu = s * 0.0078125f;
    const float var = sq * 0.0078125f - mu * mu;
    const float rs = rsqrtf(var + EPS_F);
    u16 ob[64];
#pragma unroll
    for (int i = 0; i < 16; ++i) {
      const float4 gg = *(const float4*)(ln_g + half * 64 + i * 4);
      const float4 bb = *(const float4*)(ln_b + half * 64 + i * 4);
      ob[i * 4 + 0] = f2bs((vals[i * 4 + 0] - mu) * rs * gg.x + bb.x);
      ob[i * 4 + 1] = f2bs((vals[i * 4 + 1] - mu) * rs * gg.y + bb.y);
      ob[i * 4 + 2] = f2bs((vals[i * 4 + 2] - mu) * rs * gg.z + bb.z);
      ob[i * 4 + 3] = f2bs((vals[i * 4 + 3] - mu) * rs * gg.w + bb.w);
    }
    uint4* dst = (uint4*)(As + row * 136 + half * 64);
    const uint4* sp = (const uint4*)ob;
#pragma unroll
    for (int i = 0; i < 8; ++i) dst[i] = sp[i];
  }
  if (t < 128) maskS[t] = mask[row0 + t];
  __syncthreads();

  const int lane = t & 63, wv = t >> 6;
  const int quad = lane >> 4, tl = lane & 15;
  const int wm = wv >> 1, wn = wv & 1;

  for (int tt = 0; tt < 5; ++tt) {
    // B fragments straight from global (L2-resident, coalesced 16B/lane)
    bf16x8 bfr[4][4];
    {
      const u16* wsrc = wb + (tt * 2 + wn) * 8192 + lane * 8;
#pragma unroll
      for (int nt = 0; nt < 4; ++nt)
#pragma unroll
        for (int ks = 0; ks < 4; ++ks)
          bfr[nt][ks] = *(const bf16x8*)(wsrc + (nt * 4 + ks) * 512);
    }

    f32x4 acc[4][4];
#pragma unroll
    for (int mt = 0; mt < 4; ++mt)
#pragma unroll
      for (int nt = 0; nt < 4; ++nt) acc[mt][nt] = (f32x4){0.f, 0.f, 0.f, 0.f};

#pragma unroll
    for (int ks = 0; ks < 4; ++ks) {
      bf16x8 af[4];
#pragma unroll
      for (int mt = 0; mt < 4; ++mt)
        af[mt] = *(const bf16x8*)(As + (wm * 64 + mt * 16 + tl) * 136 + ks * 32 + quad * 8);
#pragma unroll
      for (int mt = 0; mt < 4; ++mt)
#pragma unroll
        for (int nt = 0; nt < 4; ++nt)
          acc[mt][nt] = __builtin_amdgcn_mfma_f32_16x16x32_bf16(af[mt], bfr[nt][ks], acc[mt][nt], 0, 0, 0);
    }

    if (tt < 4) {
      __syncthreads();  // previous tile's store-phase reads of Ts are done
      // gate*mask*p, transpose into Ts as [64 h][stride 136] r
#pragma unroll
      for (int b2 = 0; b2 < 2; ++b2) {
        const int hl = wn * 32 + b2 * 16 + tl;
        const int hg = tt * 64 + hl;
        const float bp = b_ab_p[hg], bg = b_ab_g[hg];
#pragma unroll
        for (int mt = 0; mt < 4; ++mt)
#pragma unroll
          for (int rg = 0; rg < 4; ++rg) {
            const int r = wm * 64 + mt * 16 + quad * 4 + rg;
            const float p = acc[mt][2 * b2][rg] + bp;
            const float gt = acc[mt][2 * b2 + 1][rg] + bg;
            Ts[hl * 136 + r] = f2bs(sigmoidf_(gt) * maskS[r] * p);
          }
      }
      __syncthreads();
      {
        const int hl = t >> 2, qq = t & 3;
        const int hg = tt * 64 + hl;
        u16* dbuf = (tt < 2) ? a_t : b_t;
        const int hb = (tt < 2) ? hg : hg - 128;
        const uint4* src = (const uint4*)(Ts + hl * 136 + qq * 32);
        uint4* dst = (uint4*)(dbuf + (long)hb * RR + row0 + qq * 32);
#pragma unroll
        for (int i = 0; i < 4; ++i) dst[i] = src[i];
      }
      // Ts-reuse hazard handled by the sync at the top of next tile's epilogue
    } else {
#pragma unroll
      for (int nt = 0; nt < 4; ++nt) {
        const int c = wn * 64 + nt * 16 + tl;
        const float bgc = b_g[c];
#pragma unroll
        for (int mt = 0; mt < 4; ++mt)
#pragma unroll
          for (int rg = 0; rg < 4; ++rg) {
            const int r = wm * 64 + mt * 16 + quad * 4 + rg;
            g_out[(row0 + r) * (long)128 + c] = f2bs(sigmoidf_(acc[mt][nt][rg] + bgc));
          }
      }
    }
  }
}

// ---------------- Kernel C: triangle einsum ----------------
// per h: X_h = A_h * B_h^T (512x512x512), 128x128 tile per block, BK=64
__global__ __launch_bounds__(256) void k_tri(const u16* __restrict__ a_t,
                                             const u16* __restrict__ b_t,
                                             u16* __restrict__ x_t) {
  __shared__ __align__(16) u16 As[128 * 72];
  __shared__ __align__(16) u16 Bs[128 * 72];
  const int t = threadIdx.x;
  const int h = blockIdx.y;
  const int i0 = (blockIdx.x >> 2) * 128, j0 = (blockIdx.x & 3) * 128;
  const u16* Ag = a_t + (long)h * RR;
  const u16* Bg = b_t + (long)h * RR;
  const int lane = t & 63, wv = t >> 6;
  const int quad = lane >> 4, tl = lane & 15;
  const int wm = wv >> 1, wn = wv & 1;
  const int chunk = t & 7, rb = t >> 3;

  f32x4 acc[4][4];
#pragma unroll
  for (int mt = 0; mt < 4; ++mt)
#pragma unroll
    for (int nt = 0; nt < 4; ++nt) acc[mt][nt] = (f32x4){0.f, 0.f, 0.f, 0.f};

  for (int kt = 0; kt < 8; ++kt) {
    __syncthreads();
#pragma unroll
    for (int p = 0; p < 4; ++p) {
      const int row = rb + p * 32;
      *(uint4*)(As + row * 72 + chunk * 8) =
          *(const uint4*)(Ag + (long)(i0 + row) * 512 + kt * 64 + chunk * 8);
      *(uint4*)(Bs + row * 72 + chunk * 8) =
          *(const uint4*)(Bg + (long)(j0 + row) * 512 + kt * 64 + chunk * 8);
    }
    __syncthreads();
#pragma unroll
    for (int ks = 0; ks < 2; ++ks) {
      bf16x8 af[4], bfr[4];
#pragma unroll
      for (int mt = 0; mt < 4; ++mt)
        af[mt] = *(const bf16x8*)(As + (wm * 64 + mt * 16 + tl) * 72 + ks * 32 + quad * 8);
#pragma unroll
      for (int nt = 0; nt < 4; ++nt)
        bfr[nt] = *(const bf16x8*)(Bs + (wn * 64 + nt * 16 + tl) * 72 + ks * 32 + quad * 8);
#pragma unroll
      for (int mt = 0; mt < 4; ++mt)
#pragma unroll
        for (int nt = 0; nt < 4; ++nt)
          acc[mt][nt] = __builtin_amdgcn_mfma_f32_16x16x32_bf16(af[mt], bfr[nt], acc[mt][nt], 0, 0, 0);
    }
  }
#pragma unroll
  for (int mt = 0; mt < 4; ++mt)
#pragma unroll
    for (int nt = 0; nt < 4; ++nt)
#pragma unroll
      for (int rg = 0; rg < 4; ++rg) {
        const int i = i0 + wm * 64 + mt * 16 + quad * 4 + rg;
        const int j = j0 + wn * 64 + nt * 16 + tl;
        x_t[(long)h * RR + (long)i * 512 + j] = f2bs(acc[mt][nt][rg]);
      }
}

// ---------------- Kernel D: LN(x) + x@w_z^T + b_z, * gate ----------------
__global__ __launch_bounds__(256) void k_out(const u16* __restrict__ x_t,
                                             const float* __restrict__ w_z,
                                             const float* __restrict__ b_z,
                                             const float* __restrict__ ln_g,
                                             const float* __restrict__ ln_b,
                                             const u16* __restrict__ g_in,
                                             float* __restrict__ out) {
  __shared__ __align__(16) u16 Xs[128 * 136];
  __shared__ __align__(16) u16 Ws[128 * 136];
  __shared__ float lnGs[128], lnBs[128];
  const int t = threadIdx.x;
  const long row0 = (long)blockIdx.x * 128;

  if (t < 128) {
    lnGs[t] = ln_g[t];
    lnBs[t] = ln_b[t];
  }
  {  // stage X transposed: x_t[h][r] -> Xs[r][h]
    const int hb = t >> 3, rq = t & 7;
    u32 xv[4][8];
#pragma unroll
    for (int hh = 0; hh < 4; ++hh) {
      const uint4* src = (const uint4*)(x_t + (long)(hb * 4 + hh) * RR + row0 + rq * 16);
      const uint4 a = src[0], b = src[1];
      xv[hh][0] = a.x; xv[hh][1] = a.y; xv[hh][2] = a.z; xv[hh][3] = a.w;
      xv[hh][4] = b.x; xv[hh][5] = b.y; xv[hh][6] = b.z; xv[hh][7] = b.w;
    }
#pragma unroll
    for (int rr = 0; rr < 16; ++rr) {
      const int wi = rr >> 1, sh = (rr & 1) * 16;
      const u32 e0 = (xv[0][wi] >> sh) & 0xffffu;
      const u32 e1 = (xv[1][wi] >> sh) & 0xffffu;
      const u32 e2 = (xv[2][wi] >> sh) & 0xffffu;
      const u32 e3 = (xv[3][wi] >> sh) & 0xffffu;
      *(uint2*)(Xs + (rq * 16 + rr) * 136 + hb * 4) = make_uint2(e0 | (e1 << 16), e2 | (e3 << 16));
    }
  }
  {  // stage w_z fp32->bf16
    const int n = t >> 1, half = t & 1;
    const float* src = w_z + n * 128 + half * 64;
    u16* dst = Ws + n * 136 + half * 64;
#pragma unroll
    for (int i = 0; i < 16; ++i) {
      const float4 v = *(const float4*)(src + i * 4);
      dst[i * 4 + 0] = f2bs(v.x);
      dst[i * 4 + 1] = f2bs(v.y);
      dst[i * 4 + 2] = f2bs(v.z);
      dst[i * 4 + 3] = f2bs(v.w);
    }
  }
  __syncthreads();
  {  // LayerNorm over h, 2 threads per row
    const int r = t >> 1, half = t & 1;
    u16* xr = Xs + r * 136 + half * 64;
    float vals[64];
    float s = 0.f, sq = 0.f;
#pragma unroll
    for (int i = 0; i < 64; ++i) {
      const float v = bs2f(xr[i]);
      vals[i] = v;
      s += v;
      sq += v * v;
    }
    s += __shfl_xor(s, 1);
    sq += __shfl_xor(sq, 1);
    const float mu = s * 0.0078125f;
    const float var = sq * 0.0078125f - mu * mu;
    const float rs = rsqrtf(var + EPS_F);
#pragma unroll
    for (int i = 0; i < 64; ++i) {
      const int hh = half * 64 + i;
      xr[i] = f2bs((vals[i] - mu) * rs * lnGs[hh] + lnBs[hh]);
    }
  }
  __syncthreads();

  const int lane = t & 63, wv = t >> 6;
  const int quad = lane >> 4, tl = lane & 15;
  const int wm = wv >> 1, wn = wv & 1;
  f32x4 acc[4][4];
#pragma unroll
  for (int mt = 0; mt < 4; ++mt)
#pragma unroll
    for (int nt = 0; nt < 4; ++nt) acc[mt][nt] = (f32x4){0.f, 0.f, 0.f, 0.f};

#pragma unroll
  for (int ks = 0; ks < 4; ++ks) {
    bf16x8 af[4], bfr[4];
#pragma unroll
    for (int mt = 0; mt < 4; ++mt)
      af[mt] = *(const bf16x8*)(Xs + (wm * 64 + mt * 16 + tl) * 136 + ks * 32 + quad * 8);
#pragma unroll
    for (int nt = 0; nt < 4; ++nt)
      bfr[nt] = *(const bf16x8*)(Ws + (wn * 64 + nt * 16 + tl) * 136 + ks * 32 + quad * 8);
#pragma unroll
    for (int mt = 0; mt < 4; ++mt)
#pragma unroll
      for (int nt = 0; nt < 4; ++nt)
        acc[mt][nt] = __builtin_amdgcn_mfma_f32_16x16x32_bf16(af[mt], bfr[nt], acc[mt][nt], 0, 0, 0);
  }
#pragma unroll
  for (int nt = 0; nt < 4; ++nt) {
    const int c = wn * 64 + nt * 16 + tl;
    const float bz = b_z[c];
#pragma unroll
    for (int mt = 0; mt < 4; ++mt)
#pragma unroll
      for (int rg = 0; rg < 4; ++rg) {
        const int r = wm * 64 + mt * 16 + quad * 4 + rg;
        const long idx = (row0 + r) * 128 + c;
        out[idx] = (acc[mt][nt][rg] + bz) * bs2f(g_in[idx]);
      }
  }
}

extern "C" void kernel_launch(void* const* d_in, const int* in_sizes, int n_in,
                              void* d_out, int out_size, void* d_ws, size_t ws_size,
                              hipStream_t stream) {
  const float* z = (const float*)d_in[0];
  const float* mask = (const float*)d_in[1];
  const float* w_ab_p = (const float*)d_in[2];
  const float* b_ab_p = (const float*)d_in[3];
  const float* w_ab_g = (const float*)d_in[4];
  const float* b_ab_g = (const float*)d_in[5];
  const float* w_g = (const float*)d_in[6];
  const float* b_g = (const float*)d_in[7];
  const float* w_z = (const float*)d_in[8];
  const float* b_z = (const float*)d_in[9];
  const float* ln_in_g = (const float*)d_in[10];
  const float* ln_in_b = (const float*)d_in[11];
  const float* ln_out_g = (const float*)d_in[12];
  const float* ln_out_b = (const float*)d_in[13];
  float* out = (float*)d_out;

  // workspace (all bf16 u16): a_t, b_t, x_t, g (4 * 64 MB) + wb (160 KB)
  u16* a_t = (u16*)d_ws;
  u16* b_t = a_t + (size_t)RR * 128;
  u16* x_t = b_t + (size_t)RR * 128;
  u16* g_b = x_t + (size_t)RR * 128;
  u16* wb = g_b + (size_t)RR * 128;

  k_wconv<<<40, 256, 0, stream>>>(w_ab_p, w_ab_g, w_g, wb);
  k_proj<<<RR / 128, 256, 0, stream>>>(z, mask, wb, b_ab_p, b_ab_g, b_g,
                                       ln_in_g, ln_in_b, a_t, b_t, g_b);
  k_tri<<<dim3(16, 128), 256, 0, stream>>>(a_t, b_t, x_t);
  k_out<<<RR / 128, 256, 0, stream>>>(x_t, w_z, b_z, ln_out_g, ln_out_b, g_b, out);
}

// Round 4
// 491.887 us; speedup vs baseline: 1.1748x; 1.0026x over previous
//
#include <hip/hip_runtime.h>
#include <math.h>

#define NN 512
#define RR 262144  // NN*NN
#define EPS_F 1e-5f

typedef unsigned short u16;
typedef unsigned int u32;
typedef _Float16 f16;
typedef f16 f16x8 __attribute__((ext_vector_type(8)));
typedef float f32x4 __attribute__((ext_vector_type(4)));

__device__ __forceinline__ u16 f2hs(float f) {
  f16 h = (f16)f;
  return __builtin_bit_cast(u16, h);
}
__device__ __forceinline__ float hs2f(u16 u) {
  return (float)__builtin_bit_cast(f16, u);
}
__device__ __forceinline__ float sigmoidf_(float x) {
  return 1.f / (1.f + __expf(-x));
}
// async 16B/lane global->LDS. lds base must be wave-uniform; HW writes lane*16.
__device__ __forceinline__ void gload_lds16(const void* g, void* l) {
  __builtin_amdgcn_global_load_lds((const __attribute__((address_space(1))) void*)g,
                                   (__attribute__((address_space(3))) void*)l, 16, 0, 0);
}

// ---------------- Kernel W: weight convert fp32->fp16, MFMA-fragment order ----
// Slots u = 0..10239 (ab/g tiles):
//   u = ((((tt*2+wn)*4+nt)*4+ks)*64 + lane)*8 holds
//   W_tile[tt][n = wn*64+nt*16+(lane&15)][k = ks*32+(lane>>4)*8 + e].
// Slots u = 10240..12287: w_z fragments (for k_out), same sub-layout.
__global__ __launch_bounds__(256) void k_wconv(const float* __restrict__ w_ab_p,
                                               const float* __restrict__ w_ab_g,
                                               const float* __restrict__ w_g,
                                               const float* __restrict__ w_z,
                                               u16* __restrict__ wb) {
  const int u = blockIdx.x * 256 + threadIdx.x;  // 0..12287, 8 f16 each
  const float* src;
  if (u < 10240) {
    const int lane = u & 63;
    const int tl = lane & 15, quad = lane >> 4;
    const int ks = (u >> 6) & 3, nt = (u >> 8) & 3;
    const int wn = (u >> 10) & 1, tt = u >> 11;
    const int n = wn * 64 + nt * 16 + tl;
    const int k = ks * 32 + quad * 8;
    if (tt < 4) {
      const int srow = tt * 64 + ((n >> 5) << 4) + (n & 15);
      src = (((n >> 4) & 1) ? w_ab_g : w_ab_p) + srow * 128 + k;
    } else {
      src = w_g + n * 128 + k;
    }
  } else {
    const int u2 = u - 10240;  // 0..2047
    const int lane = u2 & 63;
    const int ks = (u2 >> 6) & 3, nt = (u2 >> 8) & 3, wn = (u2 >> 10) & 1;
    const int n = wn * 64 + nt * 16 + (lane & 15);
    const int k = ks * 32 + (lane >> 4) * 8;
    src = w_z + n * 128 + k;
  }
  const float4 v0 = *(const float4*)src;
  const float4 v1 = *(const float4*)(src + 4);
  u16 o[8] = {f2hs(v0.x), f2hs(v0.y), f2hs(v0.z), f2hs(v0.w),
              f2hs(v1.x), f2hs(v1.y), f2hs(v1.z), f2hs(v1.w)};
  *(uint4*)(wb + (long)u * 8) = *(uint4*)o;
}

// ---------------- Kernel B: fused LN(z) + all projections ----------------
// Stable two-pass LN (mu first, then E[(v-mu)^2]) matching the reference.
__global__ __launch_bounds__(256, 3) void k_proj(
    const float* __restrict__ z, const float* __restrict__ mask,
    const u16* __restrict__ wb, const float* __restrict__ b_ab_p,
    const float* __restrict__ b_ab_g, const float* __restrict__ b_g,
    const float* __restrict__ ln_g, const float* __restrict__ ln_b,
    u16* __restrict__ a_t, u16* __restrict__ b_t, u16* __restrict__ g_out) {
  __shared__ __align__(16) u16 As[128 * 136];
  __shared__ __align__(16) u16 Ts[64 * 136];
  __shared__ float maskS[128];
  const int t = threadIdx.x;
  const long row0 = (long)blockIdx.x * 128;

  {  // fused input LayerNorm: z fp32 -> fp16 zn tile in As. 2 threads/row.
    const int row = t >> 1, half = t & 1;
    const float* zr = z + (row0 + row) * 128 + half * 64;
    float vals[64];
    float s = 0.f;
#pragma unroll
    for (int i = 0; i < 16; ++i) {
      const float4 v = *(const float4*)(zr + i * 4);
      vals[i * 4 + 0] = v.x;
      vals[i * 4 + 1] = v.y;
      vals[i * 4 + 2] = v.z;
      vals[i * 4 + 3] = v.w;
      s += v.x + v.y + v.z + v.w;
    }
    s += __shfl_xor(s, 1);
    const float mu = s * 0.0078125f;
    float sq = 0.f;
#pragma unroll
    for (int i = 0; i < 64; ++i) {
      const float d = vals[i] - mu;
      sq += d * d;
    }
    sq += __shfl_xor(sq, 1);
    const float rs = rsqrtf(sq * 0.0078125f + EPS_F);
    u16 ob[64];
#pragma unroll
    for (int i = 0; i < 16; ++i) {
      const float4 gg = *(const float4*)(ln_g + half * 64 + i * 4);
      const float4 bb = *(const float4*)(ln_b + half * 64 + i * 4);
      ob[i * 4 + 0] = f2hs((vals[i * 4 + 0] - mu) * rs * gg.x + bb.x);
      ob[i * 4 + 1] = f2hs((vals[i * 4 + 1] - mu) * rs * gg.y + bb.y);
      ob[i * 4 + 2] = f2hs((vals[i * 4 + 2] - mu) * rs * gg.z + bb.z);
      ob[i * 4 + 3] = f2hs((vals[i * 4 + 3] - mu) * rs * gg.w + bb.w);
    }
    uint4* dst = (uint4*)(As + row * 136 + half * 64);
    const uint4* sp = (const uint4*)ob;
#pragma unroll
    for (int i = 0; i < 8; ++i) dst[i] = sp[i];
  }
  if (t < 128) maskS[t] = mask[row0 + t];
  __syncthreads();

  const int lane = t & 63, wv = t >> 6;
  const int quad = lane >> 4, tl = lane & 15;
  const int wm = wv >> 1, wn = wv & 1;

  for (int tt = 0; tt < 5; ++tt) {
    f16x8 bfr[4][4];
    {
      const u16* wsrc = wb + (tt * 2 + wn) * 8192 + lane * 8;
#pragma unroll
      for (int nt = 0; nt < 4; ++nt)
#pragma unroll
        for (int ks = 0; ks < 4; ++ks)
          bfr[nt][ks] = *(const f16x8*)(wsrc + (nt * 4 + ks) * 512);
    }

    f32x4 acc[4][4];
#pragma unroll
    for (int mt = 0; mt < 4; ++mt)
#pragma unroll
      for (int nt = 0; nt < 4; ++nt) acc[mt][nt] = (f32x4){0.f, 0.f, 0.f, 0.f};

#pragma unroll
    for (int ks = 0; ks < 4; ++ks) {
      f16x8 af[4];
#pragma unroll
      for (int mt = 0; mt < 4; ++mt)
        af[mt] = *(const f16x8*)(As + (wm * 64 + mt * 16 + tl) * 136 + ks * 32 + quad * 8);
#pragma unroll
      for (int mt = 0; mt < 4; ++mt)
#pragma unroll
        for (int nt = 0; nt < 4; ++nt)
          acc[mt][nt] = __builtin_amdgcn_mfma_f32_16x16x32_f16(af[mt], bfr[nt][ks], acc[mt][nt], 0, 0, 0);
    }

    if (tt < 4) {
      __syncthreads();  // previous tile's store-phase reads of Ts are done
#pragma unroll
      for (int b2 = 0; b2 < 2; ++b2) {
        const int hl = wn * 32 + b2 * 16 + tl;
        const int hg = tt * 64 + hl;
        const float bp = b_ab_p[hg], bg = b_ab_g[hg];
#pragma unroll
        for (int mt = 0; mt < 4; ++mt)
#pragma unroll
          for (int rg = 0; rg < 4; ++rg) {
            const int r = wm * 64 + mt * 16 + quad * 4 + rg;
            const float p = acc[mt][2 * b2][rg] + bp;
            const float gt = acc[mt][2 * b2 + 1][rg] + bg;
            Ts[hl * 136 + r] = f2hs(sigmoidf_(gt) * maskS[r] * p);
          }
      }
      __syncthreads();
      {
        const int hl = t >> 2, qq = t & 3;
        const int hg = tt * 64 + hl;
        u16* dbuf = (tt < 2) ? a_t : b_t;
        const int hb = (tt < 2) ? hg : hg - 128;
        const uint4* src = (const uint4*)(Ts + hl * 136 + qq * 32);
        uint4* dst = (uint4*)(dbuf + (long)hb * RR + row0 + qq * 32);
#pragma unroll
        for (int i = 0; i < 4; ++i) dst[i] = src[i];
      }
    } else {
#pragma unroll
      for (int nt = 0; nt < 4; ++nt) {
        const int c = wn * 64 + nt * 16 + tl;
        const float bgc = b_g[c];
#pragma unroll
        for (int mt = 0; mt < 4; ++mt)
#pragma unroll
          for (int rg = 0; rg < 4; ++rg) {
            const int r = wm * 64 + mt * 16 + quad * 4 + rg;
            g_out[(row0 + r) * (long)128 + c] = f2hs(sigmoidf_(acc[mt][nt][rg] + bgc));
          }
      }
    }
  }
}

// ---------------- Kernel C: triangle einsum ----------------
// per h: X_h = A_h * B_h^T (512x512x512), 128x128 tile per block, BK=64.
// global_load_lds width-16 into linear [128][64] LDS with bijective unit-XOR
// swizzle (inverse-swizzled source, swizzled read). XCD-chunked block swizzle.
__global__ __launch_bounds__(256, 4) void k_tri(const u16* __restrict__ a_t,
                                                const u16* __restrict__ b_t,
                                                u16* __restrict__ x_t) {
  __shared__ __align__(16) u16 As[128 * 64];
  __shared__ __align__(16) u16 Bs[128 * 64];
  const int t = threadIdx.x;
  const int bid = blockIdx.x;                    // 0..2047
  const int swz = (bid & 7) * 256 + (bid >> 3);  // XCD-chunked bijection
  const int h = swz >> 4;
  const int i0 = ((swz >> 2) & 3) * 128, j0 = (swz & 3) * 128;
  const u16* Ag = a_t + (long)h * RR;
  const u16* Bg = b_t + (long)h * RR;
  const int lane = t & 63, wv = t >> 6;
  const int quad = lane >> 4, tl = lane & 15;
  const int wm = wv >> 1, wn = wv & 1;
  const int lrow = lane >> 3;      // row within 8-row stripe (0..7)
  const int lu = lane & 7;         // 16B unit within 128B row
  const int su = lu ^ lrow;        // inverse-swizzled source unit

  f32x4 acc[4][4];
#pragma unroll
  for (int mt = 0; mt < 4; ++mt)
#pragma unroll
    for (int nt = 0; nt < 4; ++nt) acc[mt][nt] = (f32x4){0.f, 0.f, 0.f, 0.f};

  for (int kt = 0; kt < 8; ++kt) {
    if (kt) __syncthreads();  // prior ds_reads done before overwrite
#pragma unroll
    for (int it = 0; it < 4; ++it) {
      const int rbase = wv * 32 + it * 8;        // wave-uniform stripe base
      const int r = rbase + lrow;                // this lane's source row
      gload_lds16(Ag + (long)(i0 + r) * 512 + kt * 64 + su * 8, As + rbase * 64);
      gload_lds16(Bg + (long)(j0 + r) * 512 + kt * 64 + su * 8, Bs + rbase * 64);
    }
    __syncthreads();  // drains vmcnt(0): staged data visible
#pragma unroll
    for (int ks = 0; ks < 2; ++ks) {
      f16x8 af[4], bfr[4];
#pragma unroll
      for (int mt = 0; mt < 4; ++mt) {
        const int row = wm * 64 + mt * 16 + tl;
        const int unit = (ks * 4 + quad) ^ (row & 7);
        af[mt] = *(const f16x8*)(As + row * 64 + unit * 8);
      }
#pragma unroll
      for (int nt = 0; nt < 4; ++nt) {
        const int row = wn * 64 + nt * 16 + tl;
        const int unit = (ks * 4 + quad) ^ (row & 7);
        bfr[nt] = *(const f16x8*)(Bs + row * 64 + unit * 8);
      }
#pragma unroll
      for (int mt = 0; mt < 4; ++mt)
#pragma unroll
        for (int nt = 0; nt < 4; ++nt)
          acc[mt][nt] = __builtin_amdgcn_mfma_f32_16x16x32_f16(af[mt], bfr[nt], acc[mt][nt], 0, 0, 0);
    }
  }
#pragma unroll
  for (int mt = 0; mt < 4; ++mt)
#pragma unroll
    for (int nt = 0; nt < 4; ++nt)
#pragma unroll
      for (int rg = 0; rg < 4; ++rg) {
        const int i = i0 + wm * 64 + mt * 16 + quad * 4 + rg;
        const int j = j0 + wn * 64 + nt * 16 + tl;
        x_t[(long)h * RR + (long)i * 512 + j] = f2hs(acc[mt][nt][rg]);
      }
}

// ---------------- Kernel D: LN(x) + x@w_z^T + b_z, * gate ----------------
// w_z frags precomputed in wb; LDS 35.9K. Stable two-pass LN (3 vectorized
// LDS passes, no vals[] array -> low VGPR, fits 4 blocks/CU without spill).
__global__ __launch_bounds__(256, 4) void k_out(const u16* __restrict__ x_t,
                                                const u16* __restrict__ wb,
                                                const float* __restrict__ b_z,
                                                const float* __restrict__ ln_g,
                                                const float* __restrict__ ln_b,
                                                const u16* __restrict__ g_in,
                                                float* __restrict__ out) {
  __shared__ __align__(16) u16 Xs[128 * 136];
  __shared__ float lnGs[128], lnBs[128];
  const int t = threadIdx.x;
  const long row0 = (long)blockIdx.x * 128;

  if (t < 128) {
    lnGs[t] = ln_g[t];
    lnBs[t] = ln_b[t];
  }
  {  // stage X transposed: x_t[h][r] -> Xs[r][h]
    const int hb = t >> 3, rq = t & 7;
    u32 xv[4][8];
#pragma unroll
    for (int hh = 0; hh < 4; ++hh) {
      const uint4* src = (const uint4*)(x_t + (long)(hb * 4 + hh) * RR + row0 + rq * 16);
      const uint4 a = src[0], b = src[1];
      xv[hh][0] = a.x; xv[hh][1] = a.y; xv[hh][2] = a.z; xv[hh][3] = a.w;
      xv[hh][4] = b.x; xv[hh][5] = b.y; xv[hh][6] = b.z; xv[hh][7] = b.w;
    }
#pragma unroll
    for (int rr = 0; rr < 16; ++rr) {
      const int wi = rr >> 1, sh = (rr & 1) * 16;
      const u32 e0 = (xv[0][wi] >> sh) & 0xffffu;
      const u32 e1 = (xv[1][wi] >> sh) & 0xffffu;
      const u32 e2 = (xv[2][wi] >> sh) & 0xffffu;
      const u32 e3 = (xv[3][wi] >> sh) & 0xffffu;
      *(uint2*)(Xs + (rq * 16 + rr) * 136 + hb * 4) = make_uint2(e0 | (e1 << 16), e2 | (e3 << 16));
    }
  }
  __syncthreads();
  {  // LayerNorm over h, 2 threads per row, stable two-pass
    const int r = t >> 1, half = t & 1;
    u16* xr = Xs + r * 136 + half * 64;
    float s = 0.f;
#pragma unroll
    for (int i = 0; i < 8; ++i) {
      const f16x8 v = *(const f16x8*)(xr + i * 8);
#pragma unroll
      for (int j = 0; j < 8; ++j) s += (float)v[j];
    }
    s += __shfl_xor(s, 1);
    const float mu = s * 0.0078125f;
    float sq = 0.f;
#pragma unroll
    for (int i = 0; i < 8; ++i) {
      const f16x8 v = *(const f16x8*)(xr + i * 8);
#pragma unroll
      for (int j = 0; j < 8; ++j) {
        const float d = (float)v[j] - mu;
        sq += d * d;
      }
    }
    sq += __shfl_xor(sq, 1);
    const float rs = rsqrtf(sq * 0.0078125f + EPS_F);
#pragma unroll
    for (int i = 0; i < 8; ++i) {
      const f16x8 v = *(const f16x8*)(xr + i * 8);
      u16 ob[8];
#pragma unroll
      for (int j = 0; j < 8; ++j) {
        const int hh = half * 64 + i * 8 + j;
        ob[j] = f2hs(((float)v[j] - mu) * rs * lnGs[hh] + lnBs[hh]);
      }
      *(uint4*)(xr + i * 8) = *(uint4*)ob;
    }
  }
  __syncthreads();

  const int lane = t & 63, wv = t >> 6;
  const int quad = lane >> 4, tl = lane & 15;
  const int wm = wv >> 1, wn = wv & 1;
  f32x4 acc[4][4];
#pragma unroll
  for (int mt = 0; mt < 4; ++mt)
#pragma unroll
    for (int nt = 0; nt < 4; ++nt) acc[mt][nt] = (f32x4){0.f, 0.f, 0.f, 0.f};

  const u16* wzb = wb + 81920 + wn * 8192 + lane * 8;  // w_z fragment base
#pragma unroll
  for (int ks = 0; ks < 4; ++ks) {
    f16x8 af[4], bfr[4];
#pragma unroll
    for (int nt = 0; nt < 4; ++nt)
      bfr[nt] = *(const f16x8*)(wzb + (nt * 4 + ks) * 512);
#pragma unroll
    for (int mt = 0; mt < 4; ++mt)
      af[mt] = *(const f16x8*)(Xs + (wm * 64 + mt * 16 + tl) * 136 + ks * 32 + quad * 8);
#pragma unroll
    for (int mt = 0; mt < 4; ++mt)
#pragma unroll
      for (int nt = 0; nt < 4; ++nt)
        acc[mt][nt] = __builtin_amdgcn_mfma_f32_16x16x32_f16(af[mt], bfr[nt], acc[mt][nt], 0, 0, 0);
  }
#pragma unroll
  for (int nt = 0; nt < 4; ++nt) {
    const int c = wn * 64 + nt * 16 + tl;
    const float bz = b_z[c];
#pragma unroll
    for (int mt = 0; mt < 4; ++mt)
#pragma unroll
      for (int rg = 0; rg < 4; ++rg) {
        const int r = wm * 64 + mt * 16 + quad * 4 + rg;
        const long idx = (row0 + r) * 128 + c;
        out[idx] = (acc[mt][nt][rg] + bz) * hs2f(g_in[idx]);
      }
  }
}

extern "C" void kernel_launch(void* const* d_in, const int* in_sizes, int n_in,
                              void* d_out, int out_size, void* d_ws, size_t ws_size,
                              hipStream_t stream) {
  const float* z = (const float*)d_in[0];
  const float* mask = (const float*)d_in[1];
  const float* w_ab_p = (const float*)d_in[2];
  const float* b_ab_p = (const float*)d_in[3];
  const float* w_ab_g = (const float*)d_in[4];
  const float* b_ab_g = (const float*)d_in[5];
  const float* w_g = (const float*)d_in[6];
  const float* b_g = (const float*)d_in[7];
  const float* w_z = (const float*)d_in[8];
  const float* b_z = (const float*)d_in[9];
  const float* ln_in_g = (const float*)d_in[10];
  const float* ln_in_b = (const float*)d_in[11];
  const float* ln_out_g = (const float*)d_in[12];
  const float* ln_out_b = (const float*)d_in[13];
  float* out = (float*)d_out;

  // workspace (all fp16 u16): a_t, b_t, x_t, g (4 * 64 MB) + wb (192 KB)
  u16* a_t = (u16*)d_ws;
  u16* b_t = a_t + (size_t)RR * 128;
  u16* x_t = b_t + (size_t)RR * 128;
  u16* g_b = x_t + (size_t)RR * 128;
  u16* wb = g_b + (size_t)RR * 128;

  k_wconv<<<48, 256, 0, stream>>>(w_ab_p, w_ab_g, w_g, w_z, wb);
  k_proj<<<RR / 128, 256, 0, stream>>>(z, mask, wb, b_ab_p, b_ab_g, b_g,
                                       ln_in_g, ln_in_b, a_t, b_t, g_b);
  k_tri<<<2048, 256, 0, stream>>>(a_t, b_t, x_t);
  k_out<<<RR / 128, 256, 0, stream>>>(x_t, wb, b_z, ln_out_g, ln_out_b, g_b, out);
}